// Round 2
// baseline (125.913 us; speedup 1.0000x reference)
//
#include <hip/hip_runtime.h>
#include <hip/hip_bf16.h>

#define S_LEN 2048
#define DH    64
#define QB    128
#define KB    64
#define BHN   64
#define LDS_STRIDE 72   // shorts per row (64 + 8 pad) = 144 B, 16B-aligned

typedef __attribute__((ext_vector_type(8))) short short8;
typedef __attribute__((ext_vector_type(4))) float f32x4;

union Frag {
  short8   s;
  unsigned u[4];
};

// round-to-nearest-even float -> bf16 (low 16 bits of result)
__device__ __forceinline__ unsigned bf16u(float x) {
  unsigned u = __builtin_bit_cast(unsigned, x);
  return (u + 0x7FFFu + ((u >> 16) & 1u)) >> 16;
}
__device__ __forceinline__ unsigned pack2(float a, float b) {
  return bf16u(a) | (bf16u(b) << 16);
}

__global__ __launch_bounds__(256, 2)
void based_attn(const float* __restrict__ Qg,
                const float* __restrict__ Kg,
                const float* __restrict__ Vg,
                float* __restrict__ Og) {
  const int tid  = threadIdx.x;
  const int lane = tid & 63;
  const int wv   = tid >> 6;          // wave 0..3, owns q rows wv*32..wv*32+31
  const int qid  = lane & 15;
  const int g    = lane >> 4;

  const int bh = blockIdx.x;
  const int qt = (int)(gridDim.y - 1) - (int)blockIdx.y;  // heavy blocks first
  const int q0 = qt * QB;

  __shared__ short Klds[KB * LDS_STRIDE];   // [k][d] bf16
  __shared__ short Vlds[DH * LDS_STRIDE];   // transposed: [d][k] bf16

  const size_t base = (size_t)bh * S_LEN;

  // ---- Q fragments, pre-scaled by 1/sqrt(D)=0.125, kept in registers ----
  Frag qf[2][2];
  {
    const float SC = 0.125f;
#pragma unroll
    for (int hq = 0; hq < 2; ++hq) {
      const int qrow = q0 + wv * 32 + hq * 16 + qid;
      const float* qp = Qg + (base + qrow) * DH + g * 8;
#pragma unroll
      for (int c = 0; c < 2; ++c) {
        float4 f0 = *(const float4*)(qp + c * 32);
        float4 f1 = *(const float4*)(qp + c * 32 + 4);
        qf[hq][c].u[0] = pack2(f0.x * SC, f0.y * SC);
        qf[hq][c].u[1] = pack2(f0.z * SC, f0.w * SC);
        qf[hq][c].u[2] = pack2(f1.x * SC, f1.y * SC);
        qf[hq][c].u[3] = pack2(f1.z * SC, f1.w * SC);
      }
    }
  }

  // ones-column B fragment: B[k, col] = (col==0) ? 1.0bf16 : 0  -> row sums
  Frag ones;
  {
    const unsigned ov = (qid == 0) ? 0x3F803F80u : 0u;
    ones.u[0] = ov; ones.u[1] = ov; ones.u[2] = ov; ones.u[3] = ov;
  }

  f32x4 acc[2][4];   // [hq][d-subtile] PV accumulators
  f32x4 dacc[2];     // [hq] denominator accumulators (col 0 lanes meaningful)
#pragma unroll
  for (int hq = 0; hq < 2; ++hq) {
    dacc[hq] = (f32x4){0.f, 0.f, 0.f, 0.f};
#pragma unroll
    for (int n = 0; n < 4; ++n) acc[hq][n] = (f32x4){0.f, 0.f, 0.f, 0.f};
  }

  const int nt = 2 * qt + 2;          // causal tile count for this block
  for (int t = 0; t < nt; ++t) {
    const int k0 = t * KB;

    // ---- stage: waves 0-1 -> K (row-major), waves 2-3 -> V transposed ----
    if (tid < 128) {
      const int l = tid;
      const float4* src = (const float4*)(Kg + (base + k0) * DH);
#pragma unroll
      for (int i = 0; i < 8; ++i) {
        const int idx = l + i * 128;
        const int row = idx >> 4, c4 = idx & 15;
        float4 f = src[row * 16 + c4];
        *(uint2*)&Klds[row * LDS_STRIDE + c4 * 4] =
            make_uint2(pack2(f.x, f.y), pack2(f.z, f.w));
      }
    } else {
      const int l  = tid - 128;
      const int c4 = l & 15;          // d = 4*c4 .. 4*c4+3
      const int rp = l >> 4;          // k-block of 8 (0..7)
      const float4* src = (const float4*)(Vg + (base + k0) * DH);
      Frag col[4];
#pragma unroll
      for (int u = 0; u < 8; u += 2) {
        float4 a = src[(rp * 8 + u) * 16 + c4];
        float4 b = src[(rp * 8 + u + 1) * 16 + c4];
        col[0].u[u >> 1] = pack2(a.x, b.x);
        col[1].u[u >> 1] = pack2(a.y, b.y);
        col[2].u[u >> 1] = pack2(a.z, b.z);
        col[3].u[u >> 1] = pack2(a.w, b.w);
      }
#pragma unroll
      for (int j = 0; j < 4; ++j)
        *(short8*)&Vlds[(c4 * 4 + j) * LDS_STRIDE + rp * 8] = col[j].s;
    }
    __syncthreads();

    const bool masked = (t >= 2 * qt);

#pragma unroll
    for (int kk = 0; kk < KB; kk += 32) {
      if (q0 + wv * 32 + 31 < k0 + kk) continue;   // wave fully above diagonal

      // K fragments (A operand of S^T): rows kk+qid / kk+16+qid
      short8 aLo[2], aHi[2];
#pragma unroll
      for (int c = 0; c < 2; ++c) {
        aLo[c] = *(const short8*)&Klds[(kk + qid) * LDS_STRIDE + c * 32 + g * 8];
        aHi[c] = *(const short8*)&Klds[(kk + 16 + qid) * LDS_STRIDE + c * 32 + g * 8];
      }

      // S^T = K · Q^T : lane holds col=q (qid), rows k = 4g+r
      f32x4 stL[2], stH[2];
#pragma unroll
      for (int hq = 0; hq < 2; ++hq) {
        stL[hq] = (f32x4){0.f, 0.f, 0.f, 0.f};
        stH[hq] = (f32x4){0.f, 0.f, 0.f, 0.f};
#pragma unroll
        for (int c = 0; c < 2; ++c) {
          stL[hq] = __builtin_amdgcn_mfma_f32_16x16x32_bf16(aLo[c], qf[hq][c].s, stL[hq], 0, 0, 0);
          stH[hq] = __builtin_amdgcn_mfma_f32_16x16x32_bf16(aHi[c], qf[hq][c].s, stH[hq], 0, 0, 0);
        }
      }

      // p = 1 + s + 0.5 s^2, causal mask, round to bf16 pairs
      unsigned wrd[2][4];
#pragma unroll
      for (int hq = 0; hq < 2; ++hq) {
        const int qrow = q0 + wv * 32 + hq * 16 + qid;
        float pl[4], ph[4];
#pragma unroll
        for (int r = 0; r < 4; ++r) {
          float sl = stL[hq][r], sh = stH[hq][r];
          pl[r] = fmaf(sl, fmaf(sl, 0.5f, 1.0f), 1.0f);
          ph[r] = fmaf(sh, fmaf(sh, 0.5f, 1.0f), 1.0f);
          if (masked) {
            if (k0 + kk + 4 * g + r > qrow)      pl[r] = 0.f;
            if (k0 + kk + 16 + 4 * g + r > qrow) ph[r] = 0.f;
          }
        }
        wrd[hq][0] = pack2(pl[0], pl[1]);
        wrd[hq][1] = pack2(pl[2], pl[3]);
        wrd[hq][2] = pack2(ph[0], ph[1]);
        wrd[hq][3] = pack2(ph[2], ph[3]);
      }

      // In-register permutation: S^T D-layout (k=4g+r) -> PV A-layout (k=8g+j)
      Frag pa[2];
      {
        const int  sE  = qid + 32 * (g & 1);
        const int  sO  = sE + 16;
        const bool lo2 = (g < 2);
#pragma unroll
        for (int hq = 0; hq < 2; ++hq) {
          int a0 = __shfl((int)wrd[hq][0], sE), b0 = __shfl((int)wrd[hq][2], sE);
          int a1 = __shfl((int)wrd[hq][1], sE), b1 = __shfl((int)wrd[hq][3], sE);
          int a2 = __shfl((int)wrd[hq][0], sO), b2 = __shfl((int)wrd[hq][2], sO);
          int a3 = __shfl((int)wrd[hq][1], sO), b3 = __shfl((int)wrd[hq][3], sO);
          pa[hq].u[0] = (unsigned)(lo2 ? a0 : b0);
          pa[hq].u[1] = (unsigned)(lo2 ? a1 : b1);
          pa[hq].u[2] = (unsigned)(lo2 ? a2 : b2);
          pa[hq].u[3] = (unsigned)(lo2 ? a3 : b3);
        }
      }

      // PV: acc[q, d] += P · V   (B from transposed V in LDS, contiguous b128)
#pragma unroll
      for (int n = 0; n < 4; ++n) {
        short8 vb = *(const short8*)&Vlds[(n * 16 + qid) * LDS_STRIDE + kk + g * 8];
        acc[0][n] = __builtin_amdgcn_mfma_f32_16x16x32_bf16(pa[0].s, vb, acc[0][n], 0, 0, 0);
        acc[1][n] = __builtin_amdgcn_mfma_f32_16x16x32_bf16(pa[1].s, vb, acc[1][n], 0, 0, 0);
      }
      // denominator: same P against ones column -> exact num/denom consistency
      dacc[0] = __builtin_amdgcn_mfma_f32_16x16x32_bf16(pa[0].s, ones.s, dacc[0], 0, 0, 0);
      dacc[1] = __builtin_amdgcn_mfma_f32_16x16x32_bf16(pa[1].s, ones.s, dacc[1], 0, 0, 0);
    }
    __syncthreads();
  }

  // ---- epilogue: normalize and store fp32 ----
#pragma unroll
  for (int hq = 0; hq < 2; ++hq) {
#pragma unroll
    for (int r = 0; r < 4; ++r) {
      float dn  = __shfl(dacc[hq][r], 16 * g);   // denom(row 4g+r) lives in lane 16g
      float inv = 1.0f / (dn + 1e-6f);
      const int row = q0 + wv * 32 + hq * 16 + 4 * g + r;
      float* op = Og + (base + row) * DH + qid;
#pragma unroll
      for (int n = 0; n < 4; ++n) op[n * 16] = acc[hq][n][r] * inv;
    }
  }
}

extern "C" void kernel_launch(void* const* d_in, const int* in_sizes, int n_in,
                              void* d_out, int out_size, void* d_ws, size_t ws_size,
                              hipStream_t stream) {
  (void)in_sizes; (void)n_in; (void)d_ws; (void)ws_size; (void)out_size;
  const float* Q = (const float*)d_in[0];
  const float* K = (const float*)d_in[1];
  const float* V = (const float*)d_in[2];
  float* O = (float*)d_out;
  // grid.x = bh so all blocks of one (b,h) land on the same XCD (linear%8 = bh%8)
  dim3 grid(BHN, S_LEN / QB);
  based_attn<<<grid, 256, 0, stream>>>(Q, K, V, O);
}